// Round 4
// baseline (253.958 us; speedup 1.0000x reference)
//
#include <hip/hip_runtime.h>

// MV_GCN on MI355X — round 6: round-5 structure, fixed register budget.
// Round 5 proved the occupancy theory (33->77%) but __launch_bounds__(512,8)
// capped VGPR at 32 -> scratch spill (VALUBusy fell to 34%, WRITE_SIZE +1MB,
// dur 1.7x worse). Same kernel with (512,4): compiler free up to 128 VGPR,
// expected ~56-64 -> 8 waves/SIMD by HW VGPR rule, LDS 28.2 KB allows 5
// blocks/CU, wave cap -> 4 blocks/CU, no spill.

#define NB 256
#define NODES 116
#define FEAT 115
#define LENN 6670
#define SEG2 13456
#define HID 128
#define HC 512
#define HROWS 58   // output rows per block (116 / 2)
#define ASTR 116   // row stride (464 B = 29*16, float4-aligned rows)

__global__ __launch_bounds__(512, 4) void k_fused(
    const float* __restrict__ x, const int* __restrict__ ei,
    const float* __restrict__ ew,
    const float* __restrict__ W1, const float* __restrict__ b1,
    const float* __restrict__ W2, const float* __restrict__ b2,
    float* __restrict__ featws)
{
  __shared__ __align__(16) float sA[HROWS * ASTR];   // A_hat half, then M half
  __shared__ float deg[NODES];
  __shared__ float dinv[NODES];
  const int rawbid = blockIdx.x;
  // swizzle: rawbid = (b<<4)|(h<<3)|a  ->  gv = a + 8b, half = h.
  // halves of one (g,v) sit 8 apart in dispatch order -> same XCD (mod 8).
  const int a_ = rawbid & 7, h = (rawbid >> 3) & 1, b_ = rawbid >> 4;
  const int gv = a_ + 8 * b_;          // [0, 512)
  const int g = gv >> 1, v = gv & 1;
  const int rbase = h * HROWS;         // first global dst row of this block
  const int tid = threadIdx.x;

  // ---- phase 0: zero sA (58*116 = 6728 f32 = 1682 float4) and deg
  const float4 z4 = make_float4(0.f, 0.f, 0.f, 0.f);
  for (int i = tid; i < (HROWS * ASTR) / 4; i += 512) ((float4*)sA)[i] = z4;
  if (tid < NODES) deg[tid] = 0.f;
  __syncthreads();

  // ---- phase 1: one edge pass: deg[d] += w (all rows), A[d][s] += w (ours)
  const int eoff = g * SEG2 + v * LENN;
  const int nbase = g * 232 + v * 116;
  const int* __restrict__ srcp = ei + eoff;
  const int* __restrict__ dstp = ei + (size_t)NB * SEG2 + eoff;
  const float* __restrict__ wp = ew + eoff;
#pragma unroll 2
  for (int q = tid; q < (LENN / 2); q += 512) {
    int2 s2 = ((const int2*)srcp)[q];
    int2 d2 = ((const int2*)dstp)[q];
    float2 w2 = ((const float2*)wp)[q];
    const int dl0 = d2.x - nbase, dl1 = d2.y - nbase;     // 0..115
    atomicAdd(&deg[dl0], w2.x);
    atomicAdd(&deg[dl1], w2.y);
    const int r0 = dl0 - rbase, r1 = dl1 - rbase;
    if ((unsigned)r0 < HROWS) atomicAdd(&sA[r0 * ASTR + (s2.x - nbase)], w2.x);
    if ((unsigned)r1 < HROWS) atomicAdd(&sA[r1 * ASTR + (s2.y - nbase)], w2.y);
  }
  __syncthreads();

  // ---- phase 2: dinv for ALL nodes
  if (tid < NODES) dinv[tid] = rsqrtf(deg[tid] + 1.0f);   // deg + self-loop
  __syncthreads();

  // ---- phase 3: normalize our rows; fold self-loop dinv^2 into diagonal
  for (int idx = tid; idx < HROWS * ASTR; idx += 512) {
    int dl = idx / ASTR;
    int s = idx - dl * ASTR;
    int dg = rbase + dl;
    float di = dinv[dg];
    float val = sA[idx] * (di * dinv[s]);
    if (dg == s) val += di * di;
    sA[idx] = val;
  }
  __syncthreads();

  // ---- phase 4: M = A_hat(LDS f4 bcast) @ X(global per-lane, dbuf)
  const int cg64 = tid & 63, rg = tid >> 6;
  const int c0 = cg64 * 2;
  const float* __restrict__ Xg = x + (size_t)nbase * FEAT;
  const bool p0 = (c0 < FEAT);
  const bool p1 = (c0 + 1 < FEAT);

  float2 macc[8];
#pragma unroll
  for (int i = 0; i < 8; ++i) macc[i] = make_float2(0.f, 0.f);

  float2 xc[4], xn[4];
#pragma unroll
  for (int j = 0; j < 4; ++j) {
    xn[j].x = p0 ? Xg[(size_t)j * FEAT + c0] : 0.f;
    xn[j].y = p1 ? Xg[(size_t)j * FEAT + c0 + 1] : 0.f;
  }

  for (int sc = 0; sc < 29; ++sc) {          // K = 116 nodes, 29*4 exact
#pragma unroll
    for (int j = 0; j < 4; ++j) xc[j] = xn[j];
    if (sc < 28) {
      const int sn = 4 * (sc + 1);
#pragma unroll
      for (int j = 0; j < 4; ++j) {
        xn[j].x = p0 ? Xg[(size_t)(sn + j) * FEAT + c0] : 0.f;
        xn[j].y = p1 ? Xg[(size_t)(sn + j) * FEAT + c0 + 1] : 0.f;
      }
    }
    const int s0 = 4 * sc;
#pragma unroll
    for (int i = 0; i < 8; ++i) {
      int r = rg + 8 * i;
      r = (r < HROWS) ? r : (HROWS - 1);
      float4 aq = *(const float4*)&sA[r * ASTR + s0];  // wave-uniform bcast
      macc[i].x = fmaf(aq.x, xc[0].x, macc[i].x);
      macc[i].x = fmaf(aq.y, xc[1].x, macc[i].x);
      macc[i].x = fmaf(aq.z, xc[2].x, macc[i].x);
      macc[i].x = fmaf(aq.w, xc[3].x, macc[i].x);
      macc[i].y = fmaf(aq.x, xc[0].y, macc[i].y);
      macc[i].y = fmaf(aq.y, xc[1].y, macc[i].y);
      macc[i].y = fmaf(aq.z, xc[2].y, macc[i].y);
      macc[i].y = fmaf(aq.w, xc[3].y, macc[i].y);
    }
  }
  __syncthreads();   // everyone done reading A_hat

  // ---- phase 5: M overwrites sA (cols 0..115; col 115 == 0 from X pad)
  if (c0 < ASTR) {
#pragma unroll
    for (int i = 0; i < 8; ++i) {
      int r = rg + 8 * i;
      r = (r < HROWS) ? r : (HROWS - 1);   // clamped slots: same value, benign
      *(float2*)&sA[r * ASTR + c0] = macc[i];
    }
  }
  __syncthreads();

  // ---- phase 6: out = M(LDS f4 bcast) @ W(global per-lane, dbuf) + b
  const float* __restrict__ W = v ? W2 : W1;
  const float* __restrict__ bv = v ? b2 : b1;
  const float* __restrict__ Wc = W + c0;

  float2 bb = *(const float2*)(bv + c0);
  float2 acc[8];
#pragma unroll
  for (int i = 0; i < 8; ++i) acc[i] = bb;

  float2 wc[4], wn[4];
#pragma unroll
  for (int j = 0; j < 4; ++j) wn[j] = *(const float2*)(Wc + (size_t)j * HID);

  for (int kc = 0; kc < 29; ++kc) {          // k = 0..115 (M col 115 = 0)
#pragma unroll
    for (int j = 0; j < 4; ++j) wc[j] = wn[j];
    if (kc < 27) {
      const int kn = 4 * (kc + 1);
#pragma unroll
      for (int j = 0; j < 4; ++j)
        wn[j] = *(const float2*)(Wc + (size_t)(kn + j) * HID);
    } else if (kc == 27) {                   // tail rows 112..114 + zero row
#pragma unroll
      for (int j = 0; j < 3; ++j)
        wn[j] = *(const float2*)(Wc + (size_t)(112 + j) * HID);
      wn[3] = make_float2(0.f, 0.f);
    }
    const int k0 = 4 * kc;
#pragma unroll
    for (int i = 0; i < 8; ++i) {
      int r = rg + 8 * i;
      r = (r < HROWS) ? r : (HROWS - 1);
      float4 aq = *(const float4*)&sA[r * ASTR + k0];  // wave-uniform bcast
      acc[i].x = fmaf(aq.x, wc[0].x, acc[i].x);
      acc[i].x = fmaf(aq.y, wc[1].x, acc[i].x);
      acc[i].x = fmaf(aq.z, wc[2].x, acc[i].x);
      acc[i].x = fmaf(aq.w, wc[3].x, acc[i].x);
      acc[i].y = fmaf(aq.x, wc[0].y, acc[i].y);
      acc[i].y = fmaf(aq.y, wc[1].y, acc[i].y);
      acc[i].y = fmaf(aq.z, wc[2].y, acc[i].y);
      acc[i].y = fmaf(aq.w, wc[3].y, acc[i].y);
    }
  }

  // ---- phase 7: channel max across the wave (2 channels/lane)
#pragma unroll
  for (int i = 0; i < 8; ++i) {
    int r = rg + 8 * i;
    r = (r < HROWS) ? r : (HROWS - 1);
    float m = fmaxf(acc[i].x, acc[i].y);
#pragma unroll
    for (int off = 32; off >= 1; off >>= 1)
      m = fmaxf(m, __shfl_xor(m, off, 64));
    if (cg64 == 0)
      featws[g * 232 + 2 * (rbase + r) + v] = m;  // stack([x1,x2],1).reshape
  }
}

// ---------------- K2: MLP  relu(feat@W6+b6)@W7+b7 ----------------
__global__ __launch_bounds__(512) void k_mlp(
    const float* __restrict__ featws, const float* __restrict__ W6,
    const float* __restrict__ b6, const float* __restrict__ W7,
    const float* __restrict__ b7, float* __restrict__ out)
{
  __shared__ float sf[232];
  __shared__ float red[8];
  const int g = blockIdx.x, tid = threadIdx.x;
  if (tid < 232) sf[tid] = featws[g * 232 + tid];
  __syncthreads();

  float a = b6[tid];
  const float* __restrict__ w6p = W6 + tid;
#pragma unroll 8
  for (int k = 0; k < 232; ++k)
    a = fmaf(sf[k], w6p[(size_t)k * HC], a);
  a = fmaxf(a, 0.f);
  float p = a * W7[tid];
#pragma unroll
  for (int off = 32; off >= 1; off >>= 1) p += __shfl_xor(p, off, 64);
  if ((tid & 63) == 0) red[tid >> 6] = p;
  __syncthreads();
  if (tid == 0) {
    float t = b7[0];
#pragma unroll
    for (int i = 0; i < 8; ++i) t += red[i];
    out[g] = t;
  }
}

extern "C" void kernel_launch(void* const* d_in, const int* in_sizes, int n_in,
                              void* d_out, int out_size, void* d_ws, size_t ws_size,
                              hipStream_t stream)
{
  const float* x  = (const float*)d_in[0];
  const int*   ei = (const int*)d_in[1];
  const float* ew = (const float*)d_in[2];
  // d_in[3] = batch (unused by reference)
  const float* W1 = (const float*)d_in[4];
  const float* b1 = (const float*)d_in[5];
  const float* W2 = (const float*)d_in[6];
  const float* b2 = (const float*)d_in[7];
  const float* W6 = (const float*)d_in[8];
  const float* b6 = (const float*)d_in[9];
  const float* W7 = (const float*)d_in[10];
  const float* b7 = (const float*)d_in[11];

  float* featws = (float*)d_ws;                 // 256*232 f32 = 237 KB
  float* out    = (float*)d_out;

  hipLaunchKernelGGL(k_fused, dim3(4 * NB), dim3(512), 0, stream,
                     x, ei, ew, W1, b1, W2, b2, featws);
  hipLaunchKernelGGL(k_mlp,   dim3(NB),     dim3(512), 0, stream,
                     featws, W6, b6, W7, b7, out);
}

// Round 5
// 221.170 us; speedup vs baseline: 1.1482x; 1.1482x over previous
//
#include <hip/hip_runtime.h>

// MV_GCN on MI355X — round 7: monolithic (g,v) block at 1024 threads.
// Evidence: r3/r4 split doubled edge-scan + X/W streaming (154µs at 60% occ);
// r1 monolithic was ~100µs at 33% occ. This keeps r1's single-scan structure
// (LDS A_hat 116x116 = 54.3KB, row-sum degrees, one X/W stream) but with
// 1024-thread blocks: 2 blocks/CU x 16 waves = 32 waves/CU = 100% occupancy,
// per-thread FMA halved (8 float2 accs, rows rg+16i). VGPR ~36-48 <= 64 so
// full residency holds; launch_bounds(1024,4) leaves the allocator free
// (r3 proved the aggressive bound forces spill).

#define NB 256
#define NODES 116
#define FEAT 115
#define LENN 6670
#define SEG2 13456
#define HID 128
#define HC 512
#define ASTR 116   // row stride (464 B = 29*16, float4-aligned rows)

__global__ __launch_bounds__(1024, 4) void k_fused(
    const float* __restrict__ x, const int* __restrict__ ei,
    const float* __restrict__ ew,
    const float* __restrict__ W1, const float* __restrict__ b1,
    const float* __restrict__ W2, const float* __restrict__ b2,
    float* __restrict__ featws)
{
  __shared__ __align__(16) float sA[NODES * ASTR];   // A_hat, then M = A_hat@X
  __shared__ float dinv[NODES];
  const int bid = blockIdx.x;
  const int g = bid >> 1, v = bid & 1;
  const int tid = threadIdx.x;

  // ---- phase 0: zero A (116*116 = 13456 f32 = 3364 float4, exact)
  const float4 z4 = make_float4(0.f, 0.f, 0.f, 0.f);
  for (int i = tid; i < (NODES * ASTR) / 4; i += 1024) ((float4*)sA)[i] = z4;
  __syncthreads();

  // ---- phase 1: single edge scan: A_raw[d][s] += w (deg = row sums later)
  const int eoff = g * SEG2 + v * LENN;
  const int nbase = g * 232 + v * 116;
  const int* __restrict__ srcp = ei + eoff;
  const int* __restrict__ dstp = ei + (size_t)NB * SEG2 + eoff;
  const float* __restrict__ wp = ew + eoff;
#pragma unroll 2
  for (int q = tid; q < (LENN / 2); q += 1024) {
    int2 s2 = ((const int2*)srcp)[q];
    int2 d2 = ((const int2*)dstp)[q];
    float2 w2 = ((const float2*)wp)[q];
    atomicAdd(&sA[(d2.x - nbase) * ASTR + (s2.x - nbase)], w2.x);
    atomicAdd(&sA[(d2.y - nbase) * ASTR + (s2.y - nbase)], w2.y);
  }
  __syncthreads();

  // ---- phase 2: deg via row sums (4 threads/row, stride-29 starts)
  if (tid < 4 * NODES) {
    const int r = tid >> 2, q = tid & 3;
    const float* row = &sA[r * ASTR + q * 29];
    float s = 0.f;
#pragma unroll
    for (int j = 0; j < 29; ++j) s += row[j];
    s += __shfl_xor(s, 1, 64);
    s += __shfl_xor(s, 2, 64);
    if (q == 0) dinv[r] = rsqrtf(s + 1.0f);   // deg + 1 self-loop
  }
  __syncthreads();

  // ---- phase 3: normalize in place; fold self-loop dinv^2 into diagonal
  for (int idx = tid; idx < NODES * NODES; idx += 1024) {
    int d = idx / NODES;
    int s = idx - d * NODES;
    float di = dinv[d];
    float val = sA[idx] * (di * dinv[s]);
    if (d == s) val += di * di;
    sA[idx] = val;
  }
  __syncthreads();

  // ---- phase 4: M = A_hat(LDS f4 bcast) @ X(global per-lane, dbuf)
  const int cg64 = tid & 63, rg = tid >> 6;   // rg in 0..15 (16 waves)
  const int c0 = cg64 * 2;
  const float* __restrict__ Xg = x + (size_t)nbase * FEAT;
  const bool p0 = (c0 < FEAT);
  const bool p1 = (c0 + 1 < FEAT);

  float2 macc[8];
#pragma unroll
  for (int i = 0; i < 8; ++i) macc[i] = make_float2(0.f, 0.f);

  float2 xc[4], xn[4];
#pragma unroll
  for (int j = 0; j < 4; ++j) {
    xn[j].x = p0 ? Xg[(size_t)j * FEAT + c0] : 0.f;
    xn[j].y = p1 ? Xg[(size_t)j * FEAT + c0 + 1] : 0.f;
  }

  for (int sc = 0; sc < 29; ++sc) {          // K = 116 nodes, 29*4 exact
#pragma unroll
    for (int j = 0; j < 4; ++j) xc[j] = xn[j];
    if (sc < 28) {
      const int sn = 4 * (sc + 1);
#pragma unroll
      for (int j = 0; j < 4; ++j) {
        xn[j].x = p0 ? Xg[(size_t)(sn + j) * FEAT + c0] : 0.f;
        xn[j].y = p1 ? Xg[(size_t)(sn + j) * FEAT + c0 + 1] : 0.f;
      }
    }
    const int s0 = 4 * sc;
#pragma unroll
    for (int i = 0; i < 8; ++i) {
      int r = rg + 16 * i;
      r = (r < NODES) ? r : (NODES - 1);     // clamped slots: same row, benign
      float4 aq = *(const float4*)&sA[r * ASTR + s0];  // wave-uniform bcast
      macc[i].x = fmaf(aq.x, xc[0].x, macc[i].x);
      macc[i].x = fmaf(aq.y, xc[1].x, macc[i].x);
      macc[i].x = fmaf(aq.z, xc[2].x, macc[i].x);
      macc[i].x = fmaf(aq.w, xc[3].x, macc[i].x);
      macc[i].y = fmaf(aq.x, xc[0].y, macc[i].y);
      macc[i].y = fmaf(aq.y, xc[1].y, macc[i].y);
      macc[i].y = fmaf(aq.z, xc[2].y, macc[i].y);
      macc[i].y = fmaf(aq.w, xc[3].y, macc[i].y);
    }
  }
  __syncthreads();   // everyone done reading A_hat

  // ---- phase 5: M overwrites sA (cols 0..115; col 115 == 0 from X pad)
  if (c0 < ASTR) {
#pragma unroll
    for (int i = 0; i < 8; ++i) {
      int r = rg + 16 * i;
      r = (r < NODES) ? r : (NODES - 1);   // duplicate rows store same value
      *(float2*)&sA[r * ASTR + c0] = macc[i];
    }
  }
  __syncthreads();

  // ---- phase 6: out = M(LDS f4 bcast) @ W(global per-lane, dbuf) + b
  const float* __restrict__ W = v ? W2 : W1;
  const float* __restrict__ bv = v ? b2 : b1;
  const float* __restrict__ Wc = W + c0;

  float2 bb = *(const float2*)(bv + c0);
  float2 acc[8];
#pragma unroll
  for (int i = 0; i < 8; ++i) acc[i] = bb;

  float2 wc[4], wn[4];
#pragma unroll
  for (int j = 0; j < 4; ++j) wn[j] = *(const float2*)(Wc + (size_t)j * HID);

  for (int kc = 0; kc < 29; ++kc) {          // k = 0..115 (M col 115 = 0)
#pragma unroll
    for (int j = 0; j < 4; ++j) wc[j] = wn[j];
    if (kc < 27) {
      const int kn = 4 * (kc + 1);
#pragma unroll
      for (int j = 0; j < 4; ++j)
        wn[j] = *(const float2*)(Wc + (size_t)(kn + j) * HID);
    } else if (kc == 27) {                   // tail rows 112..114 + zero row
#pragma unroll
      for (int j = 0; j < 3; ++j)
        wn[j] = *(const float2*)(Wc + (size_t)(112 + j) * HID);
      wn[3] = make_float2(0.f, 0.f);
    }
    const int k0 = 4 * kc;
#pragma unroll
    for (int i = 0; i < 8; ++i) {
      int r = rg + 16 * i;
      r = (r < NODES) ? r : (NODES - 1);
      float4 aq = *(const float4*)&sA[r * ASTR + k0];  // wave-uniform bcast
      acc[i].x = fmaf(aq.x, wc[0].x, acc[i].x);
      acc[i].x = fmaf(aq.y, wc[1].x, acc[i].x);
      acc[i].x = fmaf(aq.z, wc[2].x, acc[i].x);
      acc[i].x = fmaf(aq.w, wc[3].x, acc[i].x);
      acc[i].y = fmaf(aq.x, wc[0].y, acc[i].y);
      acc[i].y = fmaf(aq.y, wc[1].y, acc[i].y);
      acc[i].y = fmaf(aq.z, wc[2].y, acc[i].y);
      acc[i].y = fmaf(aq.w, wc[3].y, acc[i].y);
    }
  }

  // ---- phase 7: channel max across the wave (2 channels/lane)
#pragma unroll
  for (int i = 0; i < 8; ++i) {
    int r = rg + 16 * i;
    r = (r < NODES) ? r : (NODES - 1);
    float m = fmaxf(acc[i].x, acc[i].y);
#pragma unroll
    for (int off = 32; off >= 1; off >>= 1)
      m = fmaxf(m, __shfl_xor(m, off, 64));
    if (cg64 == 0)
      featws[g * 232 + 2 * r + v] = m;   // stack([x1,x2],1).reshape (dups same)
  }
}

// ---------------- K2: MLP  relu(feat@W6+b6)@W7+b7 ----------------
// 1024 threads: col = tid&511, K-half = tid>>9 (116 rows each), LDS combine.
__global__ __launch_bounds__(1024) void k_mlp(
    const float* __restrict__ featws, const float* __restrict__ W6,
    const float* __restrict__ b6, const float* __restrict__ W7,
    const float* __restrict__ b7, float* __restrict__ out)
{
  __shared__ float sf[232];
  __shared__ float ph[512];
  __shared__ float red[8];
  const int g = blockIdx.x, tid = threadIdx.x;
  if (tid < 232) sf[tid] = featws[g * 232 + tid];
  __syncthreads();

  const int col = tid & 511, half = tid >> 9;
  const float* __restrict__ w6p = W6 + (size_t)(half * 116) * HC + col;
  const float* __restrict__ sfh = sf + half * 116;
  float p = 0.f;
#pragma unroll 4
  for (int k = 0; k < 116; ++k)
    p = fmaf(sfh[k], w6p[(size_t)k * HC], p);
  if (half) ph[col] = p;
  __syncthreads();

  if (!half) {
    float a = b6[col] + p + ph[col];
    a = fmaxf(a, 0.f) * W7[col];
#pragma unroll
    for (int off = 32; off >= 1; off >>= 1) a += __shfl_xor(a, off, 64);
    if ((tid & 63) == 0) red[tid >> 6] = a;
  }
  __syncthreads();
  if (tid == 0) {
    float t = b7[0];
#pragma unroll
    for (int i = 0; i < 8; ++i) t += red[i];
    out[g] = t;
  }
}

extern "C" void kernel_launch(void* const* d_in, const int* in_sizes, int n_in,
                              void* d_out, int out_size, void* d_ws, size_t ws_size,
                              hipStream_t stream)
{
  const float* x  = (const float*)d_in[0];
  const int*   ei = (const int*)d_in[1];
  const float* ew = (const float*)d_in[2];
  // d_in[3] = batch (unused by reference)
  const float* W1 = (const float*)d_in[4];
  const float* b1 = (const float*)d_in[5];
  const float* W2 = (const float*)d_in[6];
  const float* b2 = (const float*)d_in[7];
  const float* W6 = (const float*)d_in[8];
  const float* b6 = (const float*)d_in[9];
  const float* W7 = (const float*)d_in[10];
  const float* b7 = (const float*)d_in[11];

  float* featws = (float*)d_ws;                 // 256*232 f32 = 237 KB
  float* out    = (float*)d_out;

  hipLaunchKernelGGL(k_fused, dim3(2 * NB), dim3(1024), 0, stream,
                     x, ei, ew, W1, b1, W2, b2, featws);
  hipLaunchKernelGGL(k_mlp,   dim3(NB),     dim3(1024), 0, stream,
                     featws, W6, b6, W7, b7, out);
}